// Round 1
// baseline (6008.830 us; speedup 1.0000x reference)
//
#include <hip/hip_runtime.h>

#define NN 100000
#define NE 1600000
#define HID 512
#define LOW 128
#define NR  6

// ---------------------------------------------------------------------------
// Generic fp32 tiled GEMM: C = [ADD? C + ] ( relu? relu(A@B + bias) : A@B )
// A [M,K] row-major, B [K,N] row-major, C [M,N]. BM=BN=64, BK=32, 256 thr,
// 4x4 accumulators per thread. K % 32 == 0, N % 64 == 0 (holds for all calls).
// ---------------------------------------------------------------------------
template<bool ADD, bool RELU>
__global__ __launch_bounds__(256)
void gemm_f32(const float* __restrict__ A, const float* __restrict__ B,
              const float* __restrict__ bias, float* __restrict__ C,
              int M, int N, int K)
{
    constexpr int BM = 64, BN = 64, BK = 32;
    __shared__ float As[BK][BM];   // transposed A tile
    __shared__ float Bs[BK][BN];

    const int tid = threadIdx.x;
    const int tx  = tid & 15;      // n direction (16)
    const int ty  = tid >> 4;      // m direction (16)
    const int m0  = blockIdx.y * BM;
    const int n0  = blockIdx.x * BN;

    const int ar = tid >> 3;             // 0..31 (A tile row)
    const int ac = (tid & 7) << 2;       // 0,4,...,28 (A tile col, float4)
    const int br = tid >> 4;             // 0..15 (B tile row)
    const int bc = (tid & 15) << 2;      // 0..60 (B tile col, float4)

    float acc[4][4] = {};

    for (int k0 = 0; k0 < K; k0 += BK) {
        #pragma unroll
        for (int p = 0; p < 2; ++p) {
            int row = ar + p * 32;
            int gm  = m0 + row;
            float4 v = make_float4(0.f, 0.f, 0.f, 0.f);
            if (gm < M) v = *(const float4*)(A + (size_t)gm * K + k0 + ac);
            As[ac + 0][row] = v.x;
            As[ac + 1][row] = v.y;
            As[ac + 2][row] = v.z;
            As[ac + 3][row] = v.w;
        }
        #pragma unroll
        for (int p = 0; p < 2; ++p) {
            int row = br + p * 16;
            *(float4*)&Bs[row][bc] =
                *(const float4*)(B + (size_t)(k0 + row) * N + n0 + bc);
        }
        __syncthreads();

        #pragma unroll
        for (int kk = 0; kk < BK; ++kk) {
            float4 a4 = *(const float4*)&As[kk][ty << 2];
            float4 b4 = *(const float4*)&Bs[kk][tx << 2];
            float av[4] = {a4.x, a4.y, a4.z, a4.w};
            float bv[4] = {b4.x, b4.y, b4.z, b4.w};
            #pragma unroll
            for (int i = 0; i < 4; ++i)
                #pragma unroll
                for (int j = 0; j < 4; ++j)
                    acc[i][j] = fmaf(av[i], bv[j], acc[i][j]);
        }
        __syncthreads();
    }

    float4 bv4 = make_float4(0.f, 0.f, 0.f, 0.f);
    if constexpr (RELU) bv4 = *(const float4*)(bias + n0 + (tx << 2));

    #pragma unroll
    for (int i = 0; i < 4; ++i) {
        int gm = m0 + (ty << 2) + i;
        if (gm >= M) continue;
        float4 v = make_float4(acc[i][0], acc[i][1], acc[i][2], acc[i][3]);
        if constexpr (RELU) {
            v.x = fmaxf(v.x + bv4.x, 0.f);
            v.y = fmaxf(v.y + bv4.y, 0.f);
            v.z = fmaxf(v.z + bv4.z, 0.f);
            v.w = fmaxf(v.w + bv4.w, 0.f);
        }
        float4* p = (float4*)(C + (size_t)gm * N + n0 + (tx << 2));
        if constexpr (ADD) {
            float4 o = *p;
            v.x += o.x; v.y += o.y; v.z += o.z; v.w += o.w;
        }
        *p = v;
    }
}

// ---------------------------------------------------------------------------
// Edge scatter: S[dst][rel-g0][0:128] += h[src][0:128] for rel in [g0, g0+G).
// One wave per edge (wave-uniform edge scalars), 2 floats per lane.
// ---------------------------------------------------------------------------
__global__ __launch_bounds__(256)
void scatter_f32(const float* __restrict__ h, const int* __restrict__ src,
                 const int* __restrict__ dst, const int* __restrict__ typ,
                 float* __restrict__ S, int E, int g0, int G)
{
    long long gid = (long long)blockIdx.x * 256 + threadIdx.x;
    int e = (int)(gid >> 6);
    if (e >= E) return;
    int r = typ[e] - g0;
    if ((unsigned)r >= (unsigned)G) return;
    int c = ((int)gid & 63) << 1;
    float2 v = *(const float2*)(h + (size_t)src[e] * LOW + c);
    float* p = S + ((size_t)dst[e] * G + r) * LOW + c;
    atomicAdd(p + 0, v.x);
    atomicAdd(p + 1, v.y);
}

extern "C" void kernel_launch(void* const* d_in, const int* in_sizes, int n_in,
                              void* d_out, int out_size, void* d_ws, size_t ws_size,
                              hipStream_t stream)
{
    (void)in_sizes; (void)n_in; (void)out_size;

    const float* h_origin = (const float*)d_in[0];
    const int*   esrc     = (const int*)d_in[1];
    const int*   edst     = (const int*)d_in[2];
    const int*   etyp     = (const int*)d_in[3];
    const float* W_lower  = (const float*)d_in[4];
    const float* b_lower  = (const float*)d_in[5];
    const float* Wl[3]    = {(const float*)d_in[6], (const float*)d_in[8], (const float*)d_in[10]};
    const float* bl[3]    = {(const float*)d_in[7], (const float*)d_in[9], (const float*)d_in[11]};
    const float* W_upper  = (const float*)d_in[12];
    const float* b_upper  = (const float*)d_in[13];
    const float* W_skip   = (const float*)d_in[14];
    const float* b_skip   = (const float*)d_in[15];
    float*       out      = (float*)d_out;

    const size_t hElems = (size_t)NN * LOW;
    float* h0 = (float*)d_ws;
    float* h1 = h0 + hElems;
    float* S  = h1 + hElems;

    // Relation-chunk size G chosen so 2 h-buffers + S chunk fit in ws.
    int G = NR;
    while (G > 1 && (2 * hElems + (size_t)NN * G * LOW) * sizeof(float) > ws_size) --G;

    dim3 blk(256);
    auto gemmGrid = [](int M, int N) {
        return dim3((unsigned)(N / 64), (unsigned)((M + 63) / 64));
    };

    // lower: h0 = relu(h_origin @ W_lower + b_lower)   [100000,512]x[512,128]
    gemm_f32<false, true><<<gemmGrid(NN, LOW), blk, 0, stream>>>(
        h_origin, W_lower, b_lower, h0, NN, LOW, HID);

    float* hc = h0;
    float* hn = h1;
    const unsigned scatterBlocks = (unsigned)(((size_t)NE * 64 + 255) / 256);

    for (int L = 0; L < 3; ++L) {
        for (int g0 = 0; g0 < NR; g0 += G) {
            int g = (NR - g0 < G) ? (NR - g0) : G;
            hipMemsetAsync(S, 0, (size_t)NN * g * LOW * sizeof(float), stream);
            scatter_f32<<<dim3(scatterBlocks), blk, 0, stream>>>(
                hc, esrc, edst, etyp, S, NE, g0, g);

            bool first = (g0 == 0);
            bool last  = (g0 + g == NR);
            const float* Bmat = Wl[L] + (size_t)g0 * LOW * LOW;  // [g*128,128] slab
            int K = g * LOW;

            if (first && last)
                gemm_f32<false, true><<<gemmGrid(NN, LOW), blk, 0, stream>>>(
                    S, Bmat, bl[L], hn, NN, LOW, K);
            else if (first)
                gemm_f32<false, false><<<gemmGrid(NN, LOW), blk, 0, stream>>>(
                    S, Bmat, nullptr, hn, NN, LOW, K);
            else if (!last)
                gemm_f32<true, false><<<gemmGrid(NN, LOW), blk, 0, stream>>>(
                    S, Bmat, nullptr, hn, NN, LOW, K);
            else
                gemm_f32<true, true><<<gemmGrid(NN, LOW), blk, 0, stream>>>(
                    S, Bmat, bl[L], hn, NN, LOW, K);
        }
        float* t = hc; hc = hn; hn = t;
    }

    // out = relu(h_origin @ W_skip + b_skip) + relu(hc @ W_upper + b_upper)
    gemm_f32<false, true><<<gemmGrid(NN, HID), blk, 0, stream>>>(
        h_origin, W_skip, b_skip, out, NN, HID, HID);
    gemm_f32<true, true><<<gemmGrid(NN, HID), blk, 0, stream>>>(
        hc, W_upper, b_upper, out, NN, HID, LOW);
}

// Round 2
// 2823.491 us; speedup vs baseline: 2.1282x; 2.1282x over previous
//
#include <hip/hip_runtime.h>

#define NN 100000
#define NE 1600000
#define HID 512
#define LOW 128
#define NR  6

// ---------------------------------------------------------------------------
// Generic fp32 tiled GEMM: C = [ADD? C + ] ( RELU? relu(A@B + bias) : A@B )
// A [M,K] row-major, B [K,N] row-major, C [M,N]. BM=BN=64, BK=32, 256 thr,
// 4x4 accumulators per thread. K % 32 == 0, N % 64 == 0 (holds for all calls).
// ---------------------------------------------------------------------------
template<bool ADD, bool RELU>
__global__ __launch_bounds__(256)
void gemm_f32(const float* __restrict__ A, const float* __restrict__ B,
              const float* __restrict__ bias, float* __restrict__ C,
              int M, int N, int K)
{
    constexpr int BM = 64, BN = 64, BK = 32;
    __shared__ float As[BK][BM];   // transposed A tile
    __shared__ float Bs[BK][BN];

    const int tid = threadIdx.x;
    const int tx  = tid & 15;      // n direction (16)
    const int ty  = tid >> 4;      // m direction (16)
    const int m0  = blockIdx.y * BM;
    const int n0  = blockIdx.x * BN;

    const int ar = tid >> 3;             // 0..31 (A tile row)
    const int ac = (tid & 7) << 2;       // 0,4,...,28 (A tile col, float4)
    const int br = tid >> 4;             // 0..15 (B tile row)
    const int bc = (tid & 15) << 2;      // 0..60 (B tile col, float4)

    float acc[4][4] = {};

    for (int k0 = 0; k0 < K; k0 += BK) {
        #pragma unroll
        for (int p = 0; p < 2; ++p) {
            int row = ar + p * 32;
            int gm  = m0 + row;
            float4 v = make_float4(0.f, 0.f, 0.f, 0.f);
            if (gm < M) v = *(const float4*)(A + (size_t)gm * K + k0 + ac);
            As[ac + 0][row] = v.x;
            As[ac + 1][row] = v.y;
            As[ac + 2][row] = v.z;
            As[ac + 3][row] = v.w;
        }
        #pragma unroll
        for (int p = 0; p < 2; ++p) {
            int row = br + p * 16;
            *(float4*)&Bs[row][bc] =
                *(const float4*)(B + (size_t)(k0 + row) * N + n0 + bc);
        }
        __syncthreads();

        #pragma unroll
        for (int kk = 0; kk < BK; ++kk) {
            float4 a4 = *(const float4*)&As[kk][ty << 2];
            float4 b4 = *(const float4*)&Bs[kk][tx << 2];
            float av[4] = {a4.x, a4.y, a4.z, a4.w};
            float bv[4] = {b4.x, b4.y, b4.z, b4.w};
            #pragma unroll
            for (int i = 0; i < 4; ++i)
                #pragma unroll
                for (int j = 0; j < 4; ++j)
                    acc[i][j] = fmaf(av[i], bv[j], acc[i][j]);
        }
        __syncthreads();
    }

    float4 bv4 = make_float4(0.f, 0.f, 0.f, 0.f);
    if constexpr (RELU) bv4 = *(const float4*)(bias + n0 + (tx << 2));

    #pragma unroll
    for (int i = 0; i < 4; ++i) {
        int gm = m0 + (ty << 2) + i;
        if (gm >= M) continue;
        float4 v = make_float4(acc[i][0], acc[i][1], acc[i][2], acc[i][3]);
        if constexpr (RELU) {
            v.x = fmaxf(v.x + bv4.x, 0.f);
            v.y = fmaxf(v.y + bv4.y, 0.f);
            v.z = fmaxf(v.z + bv4.z, 0.f);
            v.w = fmaxf(v.w + bv4.w, 0.f);
        }
        float4* p = (float4*)(C + (size_t)gm * N + n0 + (tx << 2));
        if constexpr (ADD) {
            float4 o = *p;
            v.x += o.x; v.y += o.y; v.z += o.z; v.w += o.w;
        }
        *p = v;
    }
}

// ---------------------------------------------------------------------------
// CSR build (by dst): histogram -> single-block scan -> atomic-cursor fill.
// list entry packs src (bits 0..23) | rel (bits 24..26).
// ---------------------------------------------------------------------------
__global__ __launch_bounds__(256)
void k_hist(const int* __restrict__ dst, int* __restrict__ deg, int E)
{
    int e = blockIdx.x * 256 + threadIdx.x;
    if (e < E) atomicAdd(&deg[dst[e]], 1);
}

__global__ __launch_bounds__(1024)
void k_scan(const int* __restrict__ deg, int* __restrict__ rowstart,
            int* __restrict__ cursor, int n)
{
    __shared__ int ps[1024];
    const int t = threadIdx.x;
    const int per = (n + 1023) / 1024;
    const int lo = t * per;
    const int hi = min(lo + per, n);
    int s = 0;
    for (int i = lo; i < hi; ++i) s += deg[i];
    ps[t] = s;
    __syncthreads();
    for (int off = 1; off < 1024; off <<= 1) {
        int v = (t >= off) ? ps[t - off] : 0;
        __syncthreads();
        ps[t] += v;
        __syncthreads();
    }
    int run = (t > 0) ? ps[t - 1] : 0;   // exclusive offset of this chunk
    for (int i = lo; i < hi; ++i) {
        rowstart[i] = run;
        cursor[i]   = run;
        run += deg[i];
    }
}

__global__ __launch_bounds__(256)
void k_fill(const int* __restrict__ src, const int* __restrict__ dst,
            const int* __restrict__ typ, int* __restrict__ cursor,
            int* __restrict__ list, int E)
{
    int e = blockIdx.x * 256 + threadIdx.x;
    if (e < E) {
        int pos = atomicAdd(&cursor[dst[e]], 1);
        list[pos] = src[e] | (typ[e] << 24);
    }
}

// ---------------------------------------------------------------------------
// Gather-aggregate: one 128-thread block per dst node v; lane c owns channel c.
// acc[r] kept in 6 NAMED registers (no runtime-indexed array -> no scratch).
// Writes S[v][r][0:128] for all 6 r (covers every element -> no memset).
// ---------------------------------------------------------------------------
__global__ __launch_bounds__(128)
void gather_agg(const float* __restrict__ h, const int* __restrict__ rowstart,
                const int* __restrict__ deg, const int* __restrict__ list,
                float* __restrict__ S)
{
    __shared__ int sl[128];
    const int v = blockIdx.x;
    const int c = threadIdx.x;
    const int base = rowstart[v];
    const int d    = deg[v];

    float a0 = 0.f, a1 = 0.f, a2 = 0.f, a3 = 0.f, a4 = 0.f, a5 = 0.f;

    for (int i0 = 0; i0 < d; i0 += 128) {
        const int n = min(d - i0, 128);
        if (c < n) sl[c] = list[base + i0 + c];
        __syncthreads();

        int i = 0;
        for (; i + 4 <= n; i += 4) {
            int p0 = sl[i], p1 = sl[i + 1], p2 = sl[i + 2], p3 = sl[i + 3];
            float x0 = h[(size_t)(p0 & 0xFFFFFF) * LOW + c];
            float x1 = h[(size_t)(p1 & 0xFFFFFF) * LOW + c];
            float x2 = h[(size_t)(p2 & 0xFFFFFF) * LOW + c];
            float x3 = h[(size_t)(p3 & 0xFFFFFF) * LOW + c];
            int r0 = p0 >> 24, r1 = p1 >> 24, r2 = p2 >> 24, r3 = p3 >> 24;
            a0 += (r0 == 0) ? x0 : 0.f; a1 += (r0 == 1) ? x0 : 0.f;
            a2 += (r0 == 2) ? x0 : 0.f; a3 += (r0 == 3) ? x0 : 0.f;
            a4 += (r0 == 4) ? x0 : 0.f; a5 += (r0 == 5) ? x0 : 0.f;
            a0 += (r1 == 0) ? x1 : 0.f; a1 += (r1 == 1) ? x1 : 0.f;
            a2 += (r1 == 2) ? x1 : 0.f; a3 += (r1 == 3) ? x1 : 0.f;
            a4 += (r1 == 4) ? x1 : 0.f; a5 += (r1 == 5) ? x1 : 0.f;
            a0 += (r2 == 0) ? x2 : 0.f; a1 += (r2 == 1) ? x2 : 0.f;
            a2 += (r2 == 2) ? x2 : 0.f; a3 += (r2 == 3) ? x2 : 0.f;
            a4 += (r2 == 4) ? x2 : 0.f; a5 += (r2 == 5) ? x2 : 0.f;
            a0 += (r3 == 0) ? x3 : 0.f; a1 += (r3 == 1) ? x3 : 0.f;
            a2 += (r3 == 2) ? x3 : 0.f; a3 += (r3 == 3) ? x3 : 0.f;
            a4 += (r3 == 4) ? x3 : 0.f; a5 += (r3 == 5) ? x3 : 0.f;
        }
        for (; i < n; ++i) {
            int p = sl[i];
            float x = h[(size_t)(p & 0xFFFFFF) * LOW + c];
            int r = p >> 24;
            a0 += (r == 0) ? x : 0.f; a1 += (r == 1) ? x : 0.f;
            a2 += (r == 2) ? x : 0.f; a3 += (r == 3) ? x : 0.f;
            a4 += (r == 4) ? x : 0.f; a5 += (r == 5) ? x : 0.f;
        }
        __syncthreads();
    }

    float* o = S + (size_t)v * (NR * LOW) + c;
    o[0 * LOW] = a0; o[1 * LOW] = a1; o[2 * LOW] = a2;
    o[3 * LOW] = a3; o[4 * LOW] = a4; o[5 * LOW] = a5;
}

extern "C" void kernel_launch(void* const* d_in, const int* in_sizes, int n_in,
                              void* d_out, int out_size, void* d_ws, size_t ws_size,
                              hipStream_t stream)
{
    (void)in_sizes; (void)n_in; (void)out_size; (void)ws_size;

    const float* h_origin = (const float*)d_in[0];
    const int*   esrc     = (const int*)d_in[1];
    const int*   edst     = (const int*)d_in[2];
    const int*   etyp     = (const int*)d_in[3];
    const float* W_lower  = (const float*)d_in[4];
    const float* b_lower  = (const float*)d_in[5];
    const float* Wl[3]    = {(const float*)d_in[6], (const float*)d_in[8], (const float*)d_in[10]};
    const float* bl[3]    = {(const float*)d_in[7], (const float*)d_in[9], (const float*)d_in[11]};
    const float* W_upper  = (const float*)d_in[12];
    const float* b_upper  = (const float*)d_in[13];
    const float* W_skip   = (const float*)d_in[14];
    const float* b_skip   = (const float*)d_in[15];
    float*       out      = (float*)d_out;

    // Workspace layout (~366 MB)
    float* h        = (float*)d_ws;                  // [NN, 128]
    float* S        = h + (size_t)NN * LOW;          // [NN, 768]
    int*   deg      = (int*)(S + (size_t)NN * NR * LOW);
    int*   rowstart = deg + NN;
    int*   cursor   = rowstart + NN;
    int*   list     = cursor + NN;                   // [NE]

    dim3 blk(256);
    auto gemmGrid = [](int M, int N) {
        return dim3((unsigned)(N / 64), (unsigned)((M + 63) / 64));
    };
    const unsigned eBlocks = (unsigned)((NE + 255) / 256);

    // ---- CSR build (once; shared by all 3 layers) ----
    hipMemsetAsync(deg, 0, NN * sizeof(int), stream);
    k_hist<<<dim3(eBlocks), blk, 0, stream>>>(edst, deg, NE);
    k_scan<<<dim3(1), dim3(1024), 0, stream>>>(deg, rowstart, cursor, NN);
    k_fill<<<dim3(eBlocks), blk, 0, stream>>>(esrc, edst, etyp, cursor, list, NE);

    // ---- lower: h = relu(h_origin @ W_lower + b_lower) ----
    gemm_f32<false, true><<<gemmGrid(NN, LOW), blk, 0, stream>>>(
        h_origin, W_lower, b_lower, h, NN, LOW, HID);

    // ---- 3 R-GCN layers: gather(h -> S), then h = relu(S @ W + b) ----
    for (int L = 0; L < 3; ++L) {
        gather_agg<<<dim3(NN), dim3(128), 0, stream>>>(h, rowstart, deg, list, S);
        gemm_f32<false, true><<<gemmGrid(NN, LOW), blk, 0, stream>>>(
            S, Wl[L], bl[L], h, NN, LOW, NR * LOW);
    }

    // ---- out = relu(h_origin @ W_skip + b_skip) + relu(h @ W_upper + b_upper) ----
    gemm_f32<false, true><<<gemmGrid(NN, HID), blk, 0, stream>>>(
        h_origin, W_skip, b_skip, out, NN, HID, HID);
    gemm_f32<true, true><<<gemmGrid(NN, HID), blk, 0, stream>>>(
        h, W_upper, b_upper, out, NN, HID, LOW);
}

// Round 3
// 1122.397 us; speedup vs baseline: 5.3536x; 2.5156x over previous
//
#include <hip/hip_runtime.h>
#include <hip/hip_bf16.h>

#define NN 100000
#define NE 1600000
#define HID 512
#define LOW 128
#define NR  6

typedef short  bf16x8 __attribute__((ext_vector_type(8)));
typedef float  f32x4  __attribute__((ext_vector_type(4)));

__device__ __forceinline__ unsigned short f2bf(float x) {
    __hip_bfloat16 h = __float2bfloat16(x);
    return __builtin_bit_cast(unsigned short, h);
}

// ---------------------------------------------------------------------------
// Tile staging: global bf16 [rows][Kstride] -> LDS [128][64] bf16 (16 KB),
// rows are 128 B; 16B chunks XOR-swizzled by (row&7) via pre-swizzled SOURCE
// (global_load_lds writes linearly: wave-uniform base + lane*16).
// ---------------------------------------------------------------------------
__device__ __forceinline__ void stage_tile(const unsigned short* __restrict__ G,
                                           int r0, int k0, int Kstride, int Rmax,
                                           char* lds_base, int tid)
{
    #pragma unroll
    for (int is = 0; is < 4; ++is) {
        int L   = is * 4096 + tid * 16;
        int row = L >> 7;
        int c   = ((L >> 4) & 7) ^ (row & 7);
        int gr  = r0 + row;
        gr = (gr < Rmax) ? gr : (Rmax - 1);
        const char* src = (const char*)G + ((size_t)gr * Kstride + k0) * 2 + c * 16;
        __builtin_amdgcn_global_load_lds(
            (const __attribute__((address_space(1))) void*)src,
            (__attribute__((address_space(3))) void*)(lds_base + is * 4096 + (tid & 192) * 16),
            16, 0, 0);
    }
}

// Fragment read: logical (row, 16B-chunk clog) with the same XOR swizzle.
__device__ __forceinline__ bf16x8 lds_frag(const char* lds_base, int row, int clog)
{
    return *(const bf16x8*)(lds_base + row * 128 + ((clog ^ (row & 7)) << 4));
}

// ---------------------------------------------------------------------------
// bf16 MFMA GEMM: C(bf16) = relu(A @ Bt^T + bias). A [M,K] bf16 row-major,
// Bt [N,K] bf16 row-major (pre-transposed weight). 128x128 tile, 4 waves,
// each wave 64x64 via 4x4 frags of mfma_f32_16x16x32_bf16. BK=64.
// ---------------------------------------------------------------------------
__global__ __launch_bounds__(256, 2)
void gemm_bf16(const unsigned short* __restrict__ A,
               const unsigned short* __restrict__ Bt,
               const float* __restrict__ bias,
               unsigned short* __restrict__ C,
               int M, int N, int K)
{
    __shared__ __align__(16) char lA[16384];
    __shared__ __align__(16) char lB[16384];

    const int tid  = threadIdx.x;
    const int lane = tid & 63;
    const int wid  = tid >> 6;
    const int wm   = wid >> 1;
    const int wn   = wid & 1;
    const int m0   = blockIdx.y * 128;
    const int n0   = blockIdx.x * 128;

    f32x4 acc[4][4] = {};

    for (int k0 = 0; k0 < K; k0 += 64) {
        stage_tile(A,  m0, k0, K, M, lA, tid);
        stage_tile(Bt, n0, k0, K, N, lB, tid);
        __syncthreads();
        #pragma unroll
        for (int kk = 0; kk < 2; ++kk) {
            const int clog = kk * 4 + (lane >> 4);
            bf16x8 af[4], bfr[4];
            #pragma unroll
            for (int i = 0; i < 4; ++i)
                af[i] = lds_frag(lA, wm * 64 + i * 16 + (lane & 15), clog);
            #pragma unroll
            for (int j = 0; j < 4; ++j)
                bfr[j] = lds_frag(lB, wn * 64 + j * 16 + (lane & 15), clog);
            #pragma unroll
            for (int i = 0; i < 4; ++i)
                #pragma unroll
                for (int j = 0; j < 4; ++j)
                    acc[i][j] = __builtin_amdgcn_mfma_f32_16x16x32_bf16(
                        af[i], bfr[j], acc[i][j], 0, 0, 0);
        }
        __syncthreads();
    }

    const int col_l = lane & 15;
    const int rgrp  = lane >> 4;
    #pragma unroll
    for (int i = 0; i < 4; ++i) {
        #pragma unroll
        for (int j = 0; j < 4; ++j) {
            int col  = n0 + wn * 64 + j * 16 + col_l;
            float bv = bias[col];
            #pragma unroll
            for (int r = 0; r < 4; ++r) {
                int row = m0 + wm * 64 + i * 16 + rgrp * 4 + r;
                if (row < M)
                    C[(size_t)row * N + col] = f2bf(fmaxf(acc[i][j][r] + bv, 0.f));
            }
        }
    }
}

// ---------------------------------------------------------------------------
// Fused output: out(f32) = relu(h @ Wut^T + bu) + relu(hob @ Wst^T + bs)
// h [M,128] bf16, Wut [512,128] bf16; hob [M,512] bf16, Wst [512,512] bf16.
// ---------------------------------------------------------------------------
__global__ __launch_bounds__(256, 2)
void gemm_out_fused(const unsigned short* __restrict__ h,
                    const unsigned short* __restrict__ Wut,
                    const float* __restrict__ bu,
                    const unsigned short* __restrict__ hob,
                    const unsigned short* __restrict__ Wst,
                    const float* __restrict__ bs,
                    float* __restrict__ out, int M)
{
    __shared__ __align__(16) char lA[16384];
    __shared__ __align__(16) char lB[16384];

    const int tid  = threadIdx.x;
    const int lane = tid & 63;
    const int wid  = tid >> 6;
    const int wm   = wid >> 1;
    const int wn   = wid & 1;
    const int m0   = blockIdx.y * 128;
    const int n0   = blockIdx.x * 128;

    f32x4 acc1[4][4] = {};
    f32x4 acc2[4][4] = {};

    // phase 1: h @ Wut^T, K=128
    for (int k0 = 0; k0 < LOW; k0 += 64) {
        stage_tile(h,   m0, k0, LOW, M,   lA, tid);
        stage_tile(Wut, n0, k0, LOW, HID, lB, tid);
        __syncthreads();
        #pragma unroll
        for (int kk = 0; kk < 2; ++kk) {
            const int clog = kk * 4 + (lane >> 4);
            bf16x8 af[4], bfr[4];
            #pragma unroll
            for (int i = 0; i < 4; ++i)
                af[i] = lds_frag(lA, wm * 64 + i * 16 + (lane & 15), clog);
            #pragma unroll
            for (int j = 0; j < 4; ++j)
                bfr[j] = lds_frag(lB, wn * 64 + j * 16 + (lane & 15), clog);
            #pragma unroll
            for (int i = 0; i < 4; ++i)
                #pragma unroll
                for (int j = 0; j < 4; ++j)
                    acc1[i][j] = __builtin_amdgcn_mfma_f32_16x16x32_bf16(
                        af[i], bfr[j], acc1[i][j], 0, 0, 0);
        }
        __syncthreads();
    }
    // phase 2: hob @ Wst^T, K=512
    for (int k0 = 0; k0 < HID; k0 += 64) {
        stage_tile(hob, m0, k0, HID, M,   lA, tid);
        stage_tile(Wst, n0, k0, HID, HID, lB, tid);
        __syncthreads();
        #pragma unroll
        for (int kk = 0; kk < 2; ++kk) {
            const int clog = kk * 4 + (lane >> 4);
            bf16x8 af[4], bfr[4];
            #pragma unroll
            for (int i = 0; i < 4; ++i)
                af[i] = lds_frag(lA, wm * 64 + i * 16 + (lane & 15), clog);
            #pragma unroll
            for (int j = 0; j < 4; ++j)
                bfr[j] = lds_frag(lB, wn * 64 + j * 16 + (lane & 15), clog);
            #pragma unroll
            for (int i = 0; i < 4; ++i)
                #pragma unroll
                for (int j = 0; j < 4; ++j)
                    acc2[i][j] = __builtin_amdgcn_mfma_f32_16x16x32_bf16(
                        af[i], bfr[j], acc2[i][j], 0, 0, 0);
        }
        __syncthreads();
    }

    const int col_l = lane & 15;
    const int rgrp  = lane >> 4;
    #pragma unroll
    for (int i = 0; i < 4; ++i) {
        #pragma unroll
        for (int j = 0; j < 4; ++j) {
            int col   = n0 + wn * 64 + j * 16 + col_l;
            float bv1 = bu[col], bv2 = bs[col];
            #pragma unroll
            for (int r = 0; r < 4; ++r) {
                int row = m0 + wm * 64 + i * 16 + rgrp * 4 + r;
                if (row < M)
                    out[(size_t)row * HID + col] =
                        fmaxf(acc1[i][j][r] + bv1, 0.f) + fmaxf(acc2[i][j][r] + bv2, 0.f);
            }
        }
    }
}

// ---------------------------------------------------------------------------
// Conversions
// ---------------------------------------------------------------------------
__global__ __launch_bounds__(256)
void conv_f32_bf16(const float4* __restrict__ in, ushort4* __restrict__ out, int n4)
{
    for (int i = blockIdx.x * 256 + threadIdx.x; i < n4; i += gridDim.x * 256) {
        float4 v = in[i];
        ushort4 o;
        o.x = f2bf(v.x); o.y = f2bf(v.y); o.z = f2bf(v.z); o.w = f2bf(v.w);
        out[i] = o;
    }
}

// Wt[c][r] = bf16(W[r][c]);  W is [R,C] f32.
__global__ __launch_bounds__(256)
void transpose_bf16(const float* __restrict__ W, unsigned short* __restrict__ Wt,
                    int R, int C)
{
    int idx = blockIdx.x * 256 + threadIdx.x;
    if (idx < R * C) {
        int r = idx / C, c = idx - r * C;
        Wt[(size_t)c * R + r] = f2bf(W[idx]);
    }
}

// ---------------------------------------------------------------------------
// CSR build (by dst)
// ---------------------------------------------------------------------------
__global__ __launch_bounds__(256)
void k_hist(const int* __restrict__ dst, int* __restrict__ deg, int E)
{
    int e = blockIdx.x * 256 + threadIdx.x;
    if (e < E) atomicAdd(&deg[dst[e]], 1);
}

__global__ __launch_bounds__(1024)
void k_scan(const int* __restrict__ deg, int* __restrict__ rowstart,
            int* __restrict__ cursor, int n)
{
    __shared__ int ps[1024];
    const int t = threadIdx.x;
    const int per = (n + 1023) / 1024;
    const int lo = t * per;
    const int hi = min(lo + per, n);
    int s = 0;
    for (int i = lo; i < hi; ++i) s += deg[i];
    ps[t] = s;
    __syncthreads();
    for (int off = 1; off < 1024; off <<= 1) {
        int v = (t >= off) ? ps[t - off] : 0;
        __syncthreads();
        ps[t] += v;
        __syncthreads();
    }
    int run = (t > 0) ? ps[t - 1] : 0;
    for (int i = lo; i < hi; ++i) {
        rowstart[i] = run;
        cursor[i]   = run;
        run += deg[i];
    }
}

__global__ __launch_bounds__(256)
void k_fill(const int* __restrict__ src, const int* __restrict__ dst,
            const int* __restrict__ typ, int* __restrict__ cursor,
            int* __restrict__ list, int E)
{
    int e = blockIdx.x * 256 + threadIdx.x;
    if (e < E) {
        int pos = atomicAdd(&cursor[dst[e]], 1);
        list[pos] = src[e] | (typ[e] << 24);
    }
}

// ---------------------------------------------------------------------------
// Gather-aggregate (bf16 h -> bf16 S), fp32 accumulate in 6 named registers.
// ---------------------------------------------------------------------------
__global__ __launch_bounds__(128)
void gather_agg(const unsigned short* __restrict__ h,
                const int* __restrict__ rowstart, const int* __restrict__ deg,
                const int* __restrict__ list, unsigned short* __restrict__ S)
{
    __shared__ int sl[128];
    const int v = blockIdx.x;
    const int c = threadIdx.x;
    const int base = rowstart[v];
    const int d    = deg[v];

    float a0 = 0.f, a1 = 0.f, a2 = 0.f, a3 = 0.f, a4 = 0.f, a5 = 0.f;

    for (int i0 = 0; i0 < d; i0 += 128) {
        const int n = min(d - i0, 128);
        if (c < n) sl[c] = list[base + i0 + c];
        __syncthreads();

        for (int i = 0; i < n; ++i) {
            int p = sl[i];
            unsigned int bits = h[(size_t)(p & 0xFFFFFF) * LOW + c];
            float x = __builtin_bit_cast(float, bits << 16);
            int r = p >> 24;
            a0 += (r == 0) ? x : 0.f; a1 += (r == 1) ? x : 0.f;
            a2 += (r == 2) ? x : 0.f; a3 += (r == 3) ? x : 0.f;
            a4 += (r == 4) ? x : 0.f; a5 += (r == 5) ? x : 0.f;
        }
        __syncthreads();
    }

    unsigned short* o = S + (size_t)v * (NR * LOW) + c;
    o[0 * LOW] = f2bf(a0); o[1 * LOW] = f2bf(a1); o[2 * LOW] = f2bf(a2);
    o[3 * LOW] = f2bf(a3); o[4 * LOW] = f2bf(a4); o[5 * LOW] = f2bf(a5);
}

extern "C" void kernel_launch(void* const* d_in, const int* in_sizes, int n_in,
                              void* d_out, int out_size, void* d_ws, size_t ws_size,
                              hipStream_t stream)
{
    (void)in_sizes; (void)n_in; (void)out_size; (void)ws_size;

    const float* h_origin = (const float*)d_in[0];
    const int*   esrc     = (const int*)d_in[1];
    const int*   edst     = (const int*)d_in[2];
    const int*   etyp     = (const int*)d_in[3];
    const float* W_lower  = (const float*)d_in[4];
    const float* b_lower  = (const float*)d_in[5];
    const float* Wl[3]    = {(const float*)d_in[6], (const float*)d_in[8], (const float*)d_in[10]};
    const float* bl[3]    = {(const float*)d_in[7], (const float*)d_in[9], (const float*)d_in[11]};
    const float* W_upper  = (const float*)d_in[12];
    const float* b_upper  = (const float*)d_in[13];
    const float* W_skip   = (const float*)d_in[14];
    const float* b_skip   = (const float*)d_in[15];
    float*       out      = (float*)d_out;

    // Workspace layout (bf16 = ushort)
    unsigned short* hob = (unsigned short*)d_ws;          // [NN,512]
    unsigned short* h   = hob + (size_t)NN * HID;         // [NN,128]
    unsigned short* S   = h + (size_t)NN * LOW;           // [NN,768]
    unsigned short* wlt = S + (size_t)NN * NR * LOW;      // [128,512]
    unsigned short* w1t = wlt + (size_t)LOW * HID;        // [128,768] x3
    unsigned short* w2t = w1t + (size_t)LOW * NR * LOW;
    unsigned short* w3t = w2t + (size_t)LOW * NR * LOW;
    unsigned short* wut = w3t + (size_t)LOW * NR * LOW;   // [512,128]
    unsigned short* wst = wut + (size_t)HID * LOW;        // [512,512]
    int* deg      = (int*)(wst + (size_t)HID * HID);
    int* rowstart = deg + NN;
    int* cursor   = rowstart + NN;
    int* list     = cursor + NN;                          // [NE]
    unsigned short* wtL[3] = {w1t, w2t, w3t};

    const unsigned eBlocks = (unsigned)((NE + 255) / 256);
    const unsigned mBlocks = (unsigned)((NN + 127) / 128);

    // ---- conversions (independent of CSR) ----
    conv_f32_bf16<<<dim3(2048), dim3(256), 0, stream>>>(
        (const float4*)h_origin, (ushort4*)hob, NN * HID / 4);
    transpose_bf16<<<dim3((HID * LOW + 255) / 256), dim3(256), 0, stream>>>(
        W_lower, wlt, HID, LOW);
    for (int L = 0; L < 3; ++L)
        transpose_bf16<<<dim3((NR * LOW * LOW + 255) / 256), dim3(256), 0, stream>>>(
            Wl[L], wtL[L], NR * LOW, LOW);
    transpose_bf16<<<dim3((LOW * HID + 255) / 256), dim3(256), 0, stream>>>(
        W_upper, wut, LOW, HID);
    transpose_bf16<<<dim3((HID * HID + 255) / 256), dim3(256), 0, stream>>>(
        W_skip, wst, HID, HID);

    // ---- CSR build ----
    hipMemsetAsync(deg, 0, NN * sizeof(int), stream);
    k_hist<<<dim3(eBlocks), dim3(256), 0, stream>>>(edst, deg, NE);
    k_scan<<<dim3(1), dim3(1024), 0, stream>>>(deg, rowstart, cursor, NN);
    k_fill<<<dim3(eBlocks), dim3(256), 0, stream>>>(esrc, edst, etyp, cursor, list, NE);

    // ---- lower: h = relu(hob @ wlt^T + b_lower), K=512, N=128 ----
    gemm_bf16<<<dim3(1, mBlocks), dim3(256), 0, stream>>>(
        hob, wlt, b_lower, h, NN, LOW, HID);

    // ---- 3 R-GCN layers ----
    for (int L = 0; L < 3; ++L) {
        gather_agg<<<dim3(NN), dim3(128), 0, stream>>>(h, rowstart, deg, list, S);
        gemm_bf16<<<dim3(1, mBlocks), dim3(256), 0, stream>>>(
            S, wtL[L], bl[L], h, NN, LOW, NR * LOW);
    }

    // ---- fused output ----
    gemm_out_fused<<<dim3(HID / 128, mBlocks), dim3(256), 0, stream>>>(
        h, wut, b_upper, hob, wst, b_skip, out, NN);
}

// Round 4
// 1079.053 us; speedup vs baseline: 5.5686x; 1.0402x over previous
//
#include <hip/hip_runtime.h>
#include <hip/hip_bf16.h>

#define NN 100000
#define NE 1600000
#define HID 512
#define LOW 128
#define NR  6
#define NBINS (NN * NR)

typedef short  bf16x8 __attribute__((ext_vector_type(8)));
typedef float  f32x4  __attribute__((ext_vector_type(4)));

__device__ __forceinline__ unsigned short f2bf(float x) {
    __hip_bfloat16 h = __float2bfloat16(x);
    return __builtin_bit_cast(unsigned short, h);
}
__device__ __forceinline__ float bf2f(unsigned short u) {
    return __builtin_bit_cast(float, (unsigned int)u << 16);
}

// ---------------------------------------------------------------------------
// Tile staging: global bf16 [rows][Kstride] -> LDS [128][64] bf16 (16 KB),
// rows are 128 B; 16B chunks XOR-swizzled by (row&7) via pre-swizzled SOURCE
// (global_load_lds writes linearly: wave-uniform base + lane*16).
// ---------------------------------------------------------------------------
__device__ __forceinline__ void stage_tile(const unsigned short* __restrict__ G,
                                           int r0, int k0, int Kstride, int Rmax,
                                           char* lds_base, int tid)
{
    #pragma unroll
    for (int is = 0; is < 4; ++is) {
        int L   = is * 4096 + tid * 16;
        int row = L >> 7;
        int c   = ((L >> 4) & 7) ^ (row & 7);
        int gr  = r0 + row;
        gr = (gr < Rmax) ? gr : (Rmax - 1);
        const char* src = (const char*)G + ((size_t)gr * Kstride + k0) * 2 + c * 16;
        __builtin_amdgcn_global_load_lds(
            (const __attribute__((address_space(1))) void*)src,
            (__attribute__((address_space(3))) void*)(lds_base + is * 4096 + (tid & 192) * 16),
            16, 0, 0);
    }
}

__device__ __forceinline__ bf16x8 lds_frag(const char* lds_base, int row, int clog)
{
    return *(const bf16x8*)(lds_base + row * 128 + ((clog ^ (row & 7)) << 4));
}

// ---------------------------------------------------------------------------
// bf16 MFMA GEMM: C(bf16) = relu(A @ Bt^T + bias). 128x128 tile, 4 waves.
// ---------------------------------------------------------------------------
__global__ __launch_bounds__(256, 2)
void gemm_bf16(const unsigned short* __restrict__ A,
               const unsigned short* __restrict__ Bt,
               const float* __restrict__ bias,
               unsigned short* __restrict__ C,
               int M, int N, int K)
{
    __shared__ __align__(16) char lA[16384];
    __shared__ __align__(16) char lB[16384];

    const int tid  = threadIdx.x;
    const int lane = tid & 63;
    const int wid  = tid >> 6;
    const int wm   = wid >> 1;
    const int wn   = wid & 1;
    const int m0   = blockIdx.y * 128;
    const int n0   = blockIdx.x * 128;

    f32x4 acc[4][4] = {};

    for (int k0 = 0; k0 < K; k0 += 64) {
        stage_tile(A,  m0, k0, K, M, lA, tid);
        stage_tile(Bt, n0, k0, K, N, lB, tid);
        __syncthreads();
        #pragma unroll
        for (int kk = 0; kk < 2; ++kk) {
            const int clog = kk * 4 + (lane >> 4);
            bf16x8 af[4], bfr[4];
            #pragma unroll
            for (int i = 0; i < 4; ++i)
                af[i] = lds_frag(lA, wm * 64 + i * 16 + (lane & 15), clog);
            #pragma unroll
            for (int j = 0; j < 4; ++j)
                bfr[j] = lds_frag(lB, wn * 64 + j * 16 + (lane & 15), clog);
            #pragma unroll
            for (int i = 0; i < 4; ++i)
                #pragma unroll
                for (int j = 0; j < 4; ++j)
                    acc[i][j] = __builtin_amdgcn_mfma_f32_16x16x32_bf16(
                        af[i], bfr[j], acc[i][j], 0, 0, 0);
        }
        __syncthreads();
    }

    const int col_l = lane & 15;
    const int rgrp  = lane >> 4;
    #pragma unroll
    for (int i = 0; i < 4; ++i) {
        #pragma unroll
        for (int j = 0; j < 4; ++j) {
            int col  = n0 + wn * 64 + j * 16 + col_l;
            float bv = bias[col];
            #pragma unroll
            for (int r = 0; r < 4; ++r) {
                int row = m0 + wm * 64 + i * 16 + rgrp * 4 + r;
                if (row < M)
                    C[(size_t)row * N + col] = f2bf(fmaxf(acc[i][j][r] + bv, 0.f));
            }
        }
    }
}

// ---------------------------------------------------------------------------
// Fused output: out(f32) = relu(h @ Wut^T + bu) + relu(hob @ Wst^T + bs)
// ---------------------------------------------------------------------------
__global__ __launch_bounds__(256, 2)
void gemm_out_fused(const unsigned short* __restrict__ h,
                    const unsigned short* __restrict__ Wut,
                    const float* __restrict__ bu,
                    const unsigned short* __restrict__ hob,
                    const unsigned short* __restrict__ Wst,
                    const float* __restrict__ bs,
                    float* __restrict__ out, int M)
{
    __shared__ __align__(16) char lA[16384];
    __shared__ __align__(16) char lB[16384];

    const int tid  = threadIdx.x;
    const int lane = tid & 63;
    const int wid  = tid >> 6;
    const int wm   = wid >> 1;
    const int wn   = wid & 1;
    const int m0   = blockIdx.y * 128;
    const int n0   = blockIdx.x * 128;

    f32x4 acc1[4][4] = {};
    f32x4 acc2[4][4] = {};

    for (int k0 = 0; k0 < LOW; k0 += 64) {
        stage_tile(h,   m0, k0, LOW, M,   lA, tid);
        stage_tile(Wut, n0, k0, LOW, HID, lB, tid);
        __syncthreads();
        #pragma unroll
        for (int kk = 0; kk < 2; ++kk) {
            const int clog = kk * 4 + (lane >> 4);
            bf16x8 af[4], bfr[4];
            #pragma unroll
            for (int i = 0; i < 4; ++i)
                af[i] = lds_frag(lA, wm * 64 + i * 16 + (lane & 15), clog);
            #pragma unroll
            for (int j = 0; j < 4; ++j)
                bfr[j] = lds_frag(lB, wn * 64 + j * 16 + (lane & 15), clog);
            #pragma unroll
            for (int i = 0; i < 4; ++i)
                #pragma unroll
                for (int j = 0; j < 4; ++j)
                    acc1[i][j] = __builtin_amdgcn_mfma_f32_16x16x32_bf16(
                        af[i], bfr[j], acc1[i][j], 0, 0, 0);
        }
        __syncthreads();
    }
    for (int k0 = 0; k0 < HID; k0 += 64) {
        stage_tile(hob, m0, k0, HID, M,   lA, tid);
        stage_tile(Wst, n0, k0, HID, HID, lB, tid);
        __syncthreads();
        #pragma unroll
        for (int kk = 0; kk < 2; ++kk) {
            const int clog = kk * 4 + (lane >> 4);
            bf16x8 af[4], bfr[4];
            #pragma unroll
            for (int i = 0; i < 4; ++i)
                af[i] = lds_frag(lA, wm * 64 + i * 16 + (lane & 15), clog);
            #pragma unroll
            for (int j = 0; j < 4; ++j)
                bfr[j] = lds_frag(lB, wn * 64 + j * 16 + (lane & 15), clog);
            #pragma unroll
            for (int i = 0; i < 4; ++i)
                #pragma unroll
                for (int j = 0; j < 4; ++j)
                    acc2[i][j] = __builtin_amdgcn_mfma_f32_16x16x32_bf16(
                        af[i], bfr[j], acc2[i][j], 0, 0, 0);
        }
        __syncthreads();
    }

    const int col_l = lane & 15;
    const int rgrp  = lane >> 4;
    #pragma unroll
    for (int i = 0; i < 4; ++i) {
        #pragma unroll
        for (int j = 0; j < 4; ++j) {
            int col   = n0 + wn * 64 + j * 16 + col_l;
            float bv1 = bu[col], bv2 = bs[col];
            #pragma unroll
            for (int r = 0; r < 4; ++r) {
                int row = m0 + wm * 64 + i * 16 + rgrp * 4 + r;
                if (row < M)
                    out[(size_t)row * HID + col] =
                        fmaxf(acc1[i][j][r] + bv1, 0.f) + fmaxf(acc2[i][j][r] + bv2, 0.f);
            }
        }
    }
}

// ---------------------------------------------------------------------------
// Conversions
// ---------------------------------------------------------------------------
__global__ __launch_bounds__(256)
void conv_f32_bf16(const float4* __restrict__ in, ushort4* __restrict__ out, int n4)
{
    for (int i = blockIdx.x * 256 + threadIdx.x; i < n4; i += gridDim.x * 256) {
        float4 v = in[i];
        ushort4 o;
        o.x = f2bf(v.x); o.y = f2bf(v.y); o.z = f2bf(v.z); o.w = f2bf(v.w);
        out[i] = o;
    }
}

__global__ __launch_bounds__(256)
void transpose_bf16(const float* __restrict__ W, unsigned short* __restrict__ Wt,
                    int R, int C)
{
    int idx = blockIdx.x * 256 + threadIdx.x;
    if (idx < R * C) {
        int r = idx / C, c = idx - r * C;
        Wt[(size_t)c * R + r] = f2bf(W[idx]);
    }
}

// ---------------------------------------------------------------------------
// CSR build keyed by bin = dst*NR + rel. Parallel 3-kernel exclusive scan.
// ---------------------------------------------------------------------------
#define SCAN_VT 8
#define SCAN_BS 256
#define SCAN_CHUNK (SCAN_VT * SCAN_BS)                      // 2048
#define SCAN_NB ((NBINS + SCAN_CHUNK - 1) / SCAN_CHUNK)     // 293

__global__ __launch_bounds__(256)
void k_hist(const int* __restrict__ dst, const int* __restrict__ typ,
            int* __restrict__ deg, int E)
{
    int e = blockIdx.x * 256 + threadIdx.x;
    if (e < E) atomicAdd(&deg[dst[e] * NR + typ[e]], 1);
}

__global__ __launch_bounds__(SCAN_BS)
void k_scan_part(const int* __restrict__ deg, int* __restrict__ blocksum, int n)
{
    __shared__ int ps[SCAN_BS];
    const int t = threadIdx.x;
    const int lo = blockIdx.x * SCAN_CHUNK + t * SCAN_VT;
    int s = 0;
    #pragma unroll
    for (int k = 0; k < SCAN_VT; ++k) {
        int i = lo + k;
        if (i < n) s += deg[i];
    }
    ps[t] = s;
    __syncthreads();
    for (int off = SCAN_BS / 2; off > 0; off >>= 1) {
        if (t < off) ps[t] += ps[t + off];
        __syncthreads();
    }
    if (t == 0) blocksum[blockIdx.x] = ps[0];
}

__global__ __launch_bounds__(64)
void k_scan_mid(const int* __restrict__ blocksum, int* __restrict__ blockoff,
                int* __restrict__ rowstart, int nb, int n)
{
    if (threadIdx.x == 0) {
        int run = 0;
        for (int i = 0; i < nb; ++i) { blockoff[i] = run; run += blocksum[i]; }
        rowstart[n] = run;   // total = NE
    }
}

__global__ __launch_bounds__(SCAN_BS)
void k_scan_final(const int* __restrict__ deg, const int* __restrict__ blockoff,
                  int* __restrict__ rowstart, int* __restrict__ cursor, int n)
{
    __shared__ int ps[SCAN_BS];
    const int t = threadIdx.x;
    const int lo = blockIdx.x * SCAN_CHUNK + t * SCAN_VT;
    int local[SCAN_VT];
    int s = 0;
    #pragma unroll
    for (int k = 0; k < SCAN_VT; ++k) {
        int i = lo + k;
        int v = (i < n) ? deg[i] : 0;
        local[k] = v;
        s += v;
    }
    ps[t] = s;
    __syncthreads();
    for (int off = 1; off < SCAN_BS; off <<= 1) {
        int v = (t >= off) ? ps[t - off] : 0;
        __syncthreads();
        ps[t] += v;
        __syncthreads();
    }
    int run = blockoff[blockIdx.x] + ((t > 0) ? ps[t - 1] : 0);
    #pragma unroll
    for (int k = 0; k < SCAN_VT; ++k) {
        int i = lo + k;
        if (i < n) {
            rowstart[i] = run;
            cursor[i]   = run;
            run += local[k];
        }
    }
}

__global__ __launch_bounds__(256)
void k_fill(const int* __restrict__ src, const int* __restrict__ dst,
            const int* __restrict__ typ, int* __restrict__ cursor,
            int* __restrict__ list, int E)
{
    int e = blockIdx.x * 256 + threadIdx.x;
    if (e < E) {
        int pos = atomicAdd(&cursor[dst[e] * NR + typ[e]], 1);
        list[pos] = src[e];
    }
}

// ---------------------------------------------------------------------------
// Gather-aggregate: ONE WAVE per dst node; lane owns channels {2l, 2l+1}.
// Relations walked in contiguous CSR segments -> no per-edge select.
// ---------------------------------------------------------------------------
__global__ __launch_bounds__(256)
void gather_agg(const unsigned short* __restrict__ h,
                const int* __restrict__ rowstart,
                const int* __restrict__ list,
                unsigned short* __restrict__ S)
{
    const int v = (blockIdx.x * 256 + threadIdx.x) >> 6;
    if (v >= NN) return;
    const int lane = threadIdx.x & 63;
    const ushort2* hp = (const ushort2*)h;
    ushort2* o = (ushort2*)(S + (size_t)v * (NR * LOW));

    #pragma unroll
    for (int r = 0; r < NR; ++r) {
        const int s0 = rowstart[v * NR + r];
        const int s1 = rowstart[v * NR + r + 1];
        float ax = 0.f, ay = 0.f;
        for (int i = s0; i < s1; ++i) {
            int src = list[i];
            ushort2 u = hp[(size_t)src * 64 + lane];
            ax += bf2f(u.x);
            ay += bf2f(u.y);
        }
        ushort2 w;
        w.x = f2bf(ax);
        w.y = f2bf(ay);
        o[r * 64 + lane] = w;
    }
}

extern "C" void kernel_launch(void* const* d_in, const int* in_sizes, int n_in,
                              void* d_out, int out_size, void* d_ws, size_t ws_size,
                              hipStream_t stream)
{
    (void)in_sizes; (void)n_in; (void)out_size; (void)ws_size;

    const float* h_origin = (const float*)d_in[0];
    const int*   esrc     = (const int*)d_in[1];
    const int*   edst     = (const int*)d_in[2];
    const int*   etyp     = (const int*)d_in[3];
    const float* W_lower  = (const float*)d_in[4];
    const float* b_lower  = (const float*)d_in[5];
    const float* Wl[3]    = {(const float*)d_in[6], (const float*)d_in[8], (const float*)d_in[10]};
    const float* bl[3]    = {(const float*)d_in[7], (const float*)d_in[9], (const float*)d_in[11]};
    const float* W_upper  = (const float*)d_in[12];
    const float* b_upper  = (const float*)d_in[13];
    const float* W_skip   = (const float*)d_in[14];
    const float* b_skip   = (const float*)d_in[15];
    float*       out      = (float*)d_out;

    // Workspace layout
    unsigned short* hob = (unsigned short*)d_ws;          // [NN,512] bf16
    unsigned short* h   = hob + (size_t)NN * HID;         // [NN,128]
    unsigned short* S   = h + (size_t)NN * LOW;           // [NN,768]
    unsigned short* wlt = S + (size_t)NN * NR * LOW;      // [128,512]
    unsigned short* w1t = wlt + (size_t)LOW * HID;
    unsigned short* w2t = w1t + (size_t)LOW * NR * LOW;
    unsigned short* w3t = w2t + (size_t)LOW * NR * LOW;
    unsigned short* wut = w3t + (size_t)LOW * NR * LOW;   // [512,128]
    unsigned short* wst = wut + (size_t)HID * LOW;        // [512,512]
    int* deg      = (int*)(wst + (size_t)HID * HID);      // [NBINS]
    int* rowstart = deg + NBINS;                          // [NBINS+1]
    int* cursor   = rowstart + NBINS + 1;                 // [NBINS]
    int* list     = cursor + NBINS;                       // [NE]
    int* blocksum = list + NE;                            // [SCAN_NB]
    int* blockoff = blocksum + SCAN_NB;                   // [SCAN_NB]
    unsigned short* wtL[3] = {w1t, w2t, w3t};

    const unsigned eBlocks = (unsigned)((NE + 255) / 256);
    const unsigned mBlocks = (unsigned)((NN + 127) / 128);

    // ---- conversions ----
    conv_f32_bf16<<<dim3(2048), dim3(256), 0, stream>>>(
        (const float4*)h_origin, (ushort4*)hob, NN * HID / 4);
    transpose_bf16<<<dim3((HID * LOW + 255) / 256), dim3(256), 0, stream>>>(
        W_lower, wlt, HID, LOW);
    for (int L = 0; L < 3; ++L)
        transpose_bf16<<<dim3((NR * LOW * LOW + 255) / 256), dim3(256), 0, stream>>>(
            Wl[L], wtL[L], NR * LOW, LOW);
    transpose_bf16<<<dim3((LOW * HID + 255) / 256), dim3(256), 0, stream>>>(
        W_upper, wut, LOW, HID);
    transpose_bf16<<<dim3((HID * HID + 255) / 256), dim3(256), 0, stream>>>(
        W_skip, wst, HID, HID);

    // ---- CSR build over (dst, rel) bins ----
    hipMemsetAsync(deg, 0, NBINS * sizeof(int), stream);
    k_hist<<<dim3(eBlocks), dim3(256), 0, stream>>>(edst, etyp, deg, NE);
    k_scan_part<<<dim3(SCAN_NB), dim3(SCAN_BS), 0, stream>>>(deg, blocksum, NBINS);
    k_scan_mid<<<dim3(1), dim3(64), 0, stream>>>(blocksum, blockoff, rowstart, SCAN_NB, NBINS);
    k_scan_final<<<dim3(SCAN_NB), dim3(SCAN_BS), 0, stream>>>(deg, blockoff, rowstart, cursor, NBINS);
    k_fill<<<dim3(eBlocks), dim3(256), 0, stream>>>(esrc, edst, etyp, cursor, list, NE);

    // ---- lower: h = relu(hob @ wlt^T + b_lower) ----
    gemm_bf16<<<dim3(1, mBlocks), dim3(256), 0, stream>>>(
        hob, wlt, b_lower, h, NN, LOW, HID);

    // ---- 3 R-GCN layers ----
    const unsigned gBlocks = (unsigned)((NN * 64 + 255) / 256);
    for (int L = 0; L < 3; ++L) {
        gather_agg<<<dim3(gBlocks), dim3(256), 0, stream>>>(h, rowstart, list, S);
        gemm_bf16<<<dim3(1, mBlocks), dim3(256), 0, stream>>>(
            S, wtL[L], bl[L], h, NN, LOW, NR * LOW);
    }

    // ---- fused output ----
    gemm_out_fused<<<dim3(HID / 128, mBlocks), dim3(256), 0, stream>>>(
        h, wut, b_upper, hob, wst, b_skip, out, NN);
}